// Round 6
// baseline (526.753 us; speedup 1.0000x reference)
//
#include <hip/hip_runtime.h>

// S4D: B=8, L=4096, H=1024, N=32 complex modes. f32 in / f32 out.
// R10: stop fighting the register allocator -- design for ~44 arch VGPRs.
// History: allocator refuses >44 arch VGPRs for the scan loops; R8/R9 pins pushed
// the 32 mode constants into AGPRs with a v_accvgpr_read per use (~2x VALU issue,
// measured 204us vs 94us ideal-issue floor). Fix: constants live in LDS, re-read
// once per 4-step body via 8x ds_read_b128 (~2 issue slots/step vs 56 FMA slots).
// Blocks remapped so all 4 waves share one h-tile (bc varies per wave) -> one
// 8 KiB smodes[32][16] per block (4 KiB float2 in scan_local), staged once.
// The in-loop asm volatile("+v") on the LDS offset launders it so LICM/CSE cannot
// hoist the reads back out (which would recreate the pressure pathology).
// Register demand now ~45-55 = allocator's comfort zone; degradation mode under
// pressure is load serialization (graceful), not remat/AGPR-park (pathological).

#define B_ 8
#define L_ 4096
#define H_ 1024
#define N_ 32
#define NQ_ 8   // modes per lane (N_/4, 4 lane-groups per h)

// ---------------- kernel A: per-(h,n) mode constants ----------------
// modes[n*H+h] = (w_r, w_i, g_r, g_i); w = exp(dt*A); g = (2 Re C', -2 Im C');
// C' = (C_r + i C_i)*(w-1)/A.  wLc[n*H+h] = w^(Lc).
__global__ void modes_kernel(const float* __restrict__ log_dt,
                             const float* __restrict__ A_real,
                             const float* __restrict__ A_imag,
                             const float* __restrict__ C_real,
                             const float* __restrict__ C_imag,
                             float4* __restrict__ modes,
                             float2* __restrict__ wLc,
                             int log2Lc) {
    int t = blockIdx.x * blockDim.x + threadIdx.x;
    if (t >= H_ * N_) return;
    int h = t / N_, n = t % N_;
    float dt = expf(log_dt[h]);
    float ar = -expf(A_real[t]);
    float ai = A_imag[t];
    float cr = C_real[t];
    float ci = C_imag[t];
    float dr = ar * dt, di = ai * dt;
    float e = expf(dr);
    float sn, cs;
    sincosf(di, &sn, &cs);
    float wr = e * cs, wi = e * sn;
    float inv = 1.0f / (ar * ar + ai * ai);
    float nr = wr - 1.0f, ni = wi;
    float qr = (nr * ar + ni * ai) * inv;
    float qi = (ni * ar - nr * ai) * inv;
    float gr = 2.0f * (cr * qr - ci * qi);
    float gi = -2.0f * (cr * qi + ci * qr);
    modes[n * H_ + h] = make_float4(wr, wi, gr, gi);
    float pr = wr, pi2 = wi;
    for (int i = 0; i < log2Lc; ++i) {
        float t2r = pr * pr - pi2 * pi2;
        float t2i = 2.0f * pr * pi2;
        pr = t2r; pi2 = t2i;
    }
    wLc[n * H_ + h] = make_float2(pr, pi2);
}

// Block bid: h-tile ht = bid & 63 (h0 = ht*16), bc-group bcq = bid >> 6.
// Wave wv (0..3): bc = bcq*4 + wv. Lane: q = lane>>4 (mode quarter, 8 modes),
// k = lane&15 (h within tile). idx = bc*Lc*H + h (since b*L + c*Lc = bc*Lc).
// All 4 waves share one staged constant tile (same ht).

// 4 steps of the state recurrence for 8 modes, constants re-read from LDS.
#define SLOC_BODY(U0, U1, U2, U3, DO_PF) do {                                   \
    asm volatile("" : "+v"(soff));  /* launder: defeat LICM/CSE of LDS reads */ \
    const float2* sp_ = smw + soff;                                             \
    float2 mm[NQ_];                                                             \
    _Pragma("unroll")                                                           \
    for (int n = 0; n < NQ_; ++n) mm[n] = sp_[n * 16];                          \
    _Pragma("unroll")                                                           \
    for (int n = 0; n < NQ_; ++n) {                                             \
        const float wrn = mm[n].x, win = mm[n].y;                               \
        float t1r = fmaf(wrn, sr[n], fmaf(-win, si[n], (U0)));                  \
        float t1i = fmaf(wrn, si[n], win * sr[n]);                              \
        float t2r = fmaf(wrn, t1r, fmaf(-win, t1i, (U1)));                      \
        float t2i = fmaf(wrn, t1i, win * t1r);                                  \
        float t3r = fmaf(wrn, t2r, fmaf(-win, t2i, (U2)));                      \
        float t3i = fmaf(wrn, t2i, win * t2r);                                  \
        float t4r = fmaf(wrn, t3r, fmaf(-win, t3i, (U3)));                      \
        float t4i = fmaf(wrn, t3i, win * t3r);                                  \
        sr[n] = t4r; si[n] = t4i;                                               \
    }                                                                           \
    if (DO_PF) {                                                                \
        (U0) = u[pf]; (U1) = u[pf + H_]; (U2) = u[pf + 2u * H_];                \
        (U3) = u[pf + 3u * H_];                                                 \
        pf += 4u * H_;                                                          \
    }                                                                           \
} while (0)

// ---------------- kernel B: local scan per chunk (zero entry state) ----------------
template <int C_>
__global__ __launch_bounds__(256, 8) void scan_local(const float* __restrict__ u,
                                                     const float4* __restrict__ modes,
                                                     float2* __restrict__ states) {
    constexpr int Lc = L_ / C_;
    __shared__ float2 smw[N_ * 16];  // [n][k], 4 KiB
    int tid = threadIdx.x;
    int ht = blockIdx.x & 63;
    int bc = (blockIdx.x >> 6) * 4 + (tid >> 6);
    int lane = tid & 63;
    int q = lane >> 4;
    int k = lane & 15;
    int h = ht * 16 + k;
    int nb = q * NQ_;
    // stage constants: 512 float2, 256 threads x 2
    for (int i = tid; i < N_ * 16; i += 256) {
        float4 m = modes[(i >> 4) * H_ + ht * 16 + (i & 15)];
        smw[i] = make_float2(m.x, m.y);
    }
    __syncthreads();
    float sr[NQ_], si[NQ_];
#pragma unroll
    for (int n = 0; n < NQ_; ++n) { sr[n] = 0.0f; si[n] = 0.0f; }
    unsigned soff = (unsigned)(nb * 16 + k);
    unsigned idx = (unsigned)bc * (unsigned)(Lc * H_) + (unsigned)h;
    float a0 = u[idx];
    float a1 = u[idx + H_];
    float a2 = u[idx + 2u * H_];
    float a3 = u[idx + 3u * H_];
    float b0 = u[idx + 4u * H_];
    float b1 = u[idx + 5u * H_];
    float b2 = u[idx + 6u * H_];
    float b3 = u[idx + 7u * H_];
    unsigned pf = idx + 8u * H_;
    for (int j = 0; j + 8 < Lc; j += 8) {
        SLOC_BODY(a0, a1, a2, a3, 1);
        SLOC_BODY(b0, b1, b2, b3, 1);
    }
    SLOC_BODY(a0, a1, a2, a3, 0);
    SLOC_BODY(b0, b1, b2, b3, 0);
    float2* sp = states + ((size_t)bc * N_ + nb) * H_ + h;
#pragma unroll
    for (int n = 0; n < NQ_; ++n) sp[(size_t)n * H_] = make_float2(sr[n], si[n]);
}

// ---------------- kernel C: cross-chunk scan (in place: local-end -> entry) --------
template <int C_>
__global__ __launch_bounds__(256) void chunk_scan(const float2* __restrict__ wLc,
                                                  float2* __restrict__ states) {
    int t = blockIdx.x * blockDim.x + threadIdx.x;
    int h = t % H_;
    int bn = t / H_;
    int n = bn % N_;
    int b = bn / N_;
    float2 wl = wLc[n * H_ + h];
    float er = 0.0f, ei = 0.0f;
    float2* p0 = states + ((size_t)(b * C_) * N_ + n) * H_ + h;
    const size_t stride = (size_t)N_ * H_;
    float2 nxt = *p0;
#pragma unroll
    for (int c = 0; c < C_; ++c) {
        float2 le = nxt;
        float2* p = p0 + (size_t)c * stride;
        if (c + 1 < C_) nxt = p[stride];  // prefetch next before FMA/store
        *p = make_float2(er, ei);
        float nr2 = fmaf(wl.x, er, fmaf(-wl.y, ei, le.x));
        float ni2 = fmaf(wl.x, ei, fmaf(wl.y, er, le.y));
        er = nr2; ei = ni2;
    }
}

// 4 steps + g-accumulate + 4x4 transpose-reduce + gelu/store (one row per quarter),
// constants re-read from LDS once per body.
#define SOUT_BODY(U0, U1, U2, U3, DO_PF) do {                                   \
    asm volatile("" : "+v"(soff));  /* launder: defeat LICM/CSE of LDS reads */ \
    const float4* sp_ = smodes + soff;                                          \
    float4 mm[NQ_];                                                             \
    _Pragma("unroll")                                                           \
    for (int n = 0; n < NQ_; ++n) mm[n] = sp_[n * 16];                          \
    float accA = 0.0f, accB = 0.0f, accC = 0.0f, accD = 0.0f;                   \
    _Pragma("unroll")                                                           \
    for (int n = 0; n < NQ_; ++n) {                                             \
        const float wrn = mm[n].x, win = mm[n].y;                               \
        const float grn = mm[n].z, gin = mm[n].w;                               \
        float t1r = fmaf(wrn, sr[n], fmaf(-win, si[n], (U0)));                  \
        float t1i = fmaf(wrn, si[n], win * sr[n]);                              \
        accA = fmaf(grn, t1r, fmaf(gin, t1i, accA));                            \
        float t2r = fmaf(wrn, t1r, fmaf(-win, t1i, (U1)));                      \
        float t2i = fmaf(wrn, t1i, win * t1r);                                  \
        accB = fmaf(grn, t2r, fmaf(gin, t2i, accB));                            \
        float t3r = fmaf(wrn, t2r, fmaf(-win, t2i, (U2)));                      \
        float t3i = fmaf(wrn, t2i, win * t2r);                                  \
        accC = fmaf(grn, t3r, fmaf(gin, t3i, accC));                            \
        float t4r = fmaf(wrn, t3r, fmaf(-win, t3i, (U3)));                      \
        float t4i = fmaf(wrn, t3i, win * t3r);                                  \
        accD = fmaf(grn, t4r, fmaf(gin, t4i, accD));                            \
        sr[n] = t4r; si[n] = t4i;                                               \
    }                                                                           \
    /* stage 1 (xor 32): pair-sum A with A, B with B across half-groups */      \
    float r0 = hiq ? accC : accA;                                               \
    float r1 = hiq ? accA : accC;                                               \
    float p0 = r0 + __shfl_xor(r1, 32, 64);                                     \
    float r2 = hiq ? accD : accB;                                               \
    float r3 = hiq ? accB : accD;                                               \
    float p1 = r2 + __shfl_xor(r3, 32, 64);                                     \
    /* stage 2 (xor 16): each quarter ends with its own step's total */         \
    float snd = oddq ? p0 : p1;                                                 \
    float bse = oddq ? p1 : p0;                                                 \
    float accS = bse + __shfl_xor(snd, 16, 64);                                 \
    float uv01 = oddq ? (U1) : (U0);                                            \
    float uv23 = oddq ? (U3) : (U2);                                            \
    float uvS = hiq ? uv23 : uv01;                                              \
    float v = fmaf(Dv, uvS, accS);                                              \
    float g = 0.5f * v * (1.0f + erff(v * 0.70710678118654752f));               \
    y[sy] = g;                                                                  \
    sy += 4u * H_;                                                              \
    if (DO_PF) {                                                                \
        (U0) = u[pf]; (U1) = u[pf + H_]; (U2) = u[pf + 2u * H_];                \
        (U3) = u[pf + 3u * H_];                                                 \
        pf += 4u * H_;                                                          \
    }                                                                           \
} while (0)

// ---------------- kernel D: re-scan with entry state, emit gelu(y) ----------------
template <int C_>
__global__ __launch_bounds__(256, 6)
void scan_out(const float* __restrict__ u,
              const float4* __restrict__ modes,
              const float2* __restrict__ states,
              const float* __restrict__ Dscal,
              float* __restrict__ y) {
    constexpr int Lc = L_ / C_;
    __shared__ float4 smodes[N_ * 16];  // [n][k], 8 KiB
    int tid = threadIdx.x;
    int ht = blockIdx.x & 63;
    int bc = (blockIdx.x >> 6) * 4 + (tid >> 6);
    int lane = tid & 63;
    int q = lane >> 4;
    int k = lane & 15;
    int h = ht * 16 + k;
    int nb = q * NQ_;
    bool hiq = (lane & 32) != 0;   // quarter in {2,3}
    bool oddq = (lane & 16) != 0;  // quarter odd
    float Dv = Dscal[0];
    // stage constants: 512 float4, 256 threads x 2
    for (int i = tid; i < N_ * 16; i += 256) {
        smodes[i] = modes[(i >> 4) * H_ + ht * 16 + (i & 15)];
    }
    __syncthreads();
    float sr[NQ_], si[NQ_];
#pragma unroll
    for (int n = 0; n < NQ_; ++n) {
        float2 e = states[((size_t)bc * N_ + nb + n) * H_ + h];
        sr[n] = e.x; si[n] = e.y;
    }
    unsigned soff = (unsigned)(nb * 16 + k);
    unsigned idx = (unsigned)bc * (unsigned)(Lc * H_) + (unsigned)h;
    unsigned sy = idx + (unsigned)(q * H_);
    float a0 = u[idx];
    float a1 = u[idx + H_];
    float a2 = u[idx + 2u * H_];
    float a3 = u[idx + 3u * H_];
    float b0 = u[idx + 4u * H_];
    float b1 = u[idx + 5u * H_];
    float b2 = u[idx + 6u * H_];
    float b3 = u[idx + 7u * H_];
    unsigned pf = idx + 8u * H_;
    for (int j = 0; j + 8 < Lc; j += 8) {
        SOUT_BODY(a0, a1, a2, a3, 1);
        SOUT_BODY(b0, b1, b2, b3, 1);
    }
    SOUT_BODY(a0, a1, a2, a3, 0);
    SOUT_BODY(b0, b1, b2, b3, 0);
}

// ---------------- launcher ----------------
template <int C_>
static void launch_all(const float* u, const float* log_dt, const float* A_real,
                       const float* A_imag, const float* C_real, const float* C_imag,
                       const float* Dscal, float* y, char* ws, hipStream_t stream) {
    float4* modes = (float4*)ws;                        // H*N*16 = 512 KiB
    float2* wLc   = (float2*)(ws + 524288);             // H*N*8  = 256 KiB
    float2* states = (float2*)(ws + 786432);            // B*C*N*H*8
    int log2Lc = 0;
    for (int v = L_ / C_; v > 1; v >>= 1) ++log2Lc;

    // blocks: (B*C/4) bc-groups x 64 h-tiles; 4 waves/block share one h-tile
    constexpr int nblocks = (B_ * C_ / 4) * 64;

    modes_kernel<<<(H_ * N_) / 256, 256, 0, stream>>>(log_dt, A_real, A_imag,
                                                      C_real, C_imag, modes, wLc, log2Lc);
    scan_local<C_><<<nblocks, 256, 0, stream>>>(u, modes, states);
    chunk_scan<C_><<<(B_ * N_ * H_) / 256, 256, 0, stream>>>(wLc, states);
    scan_out<C_><<<nblocks, 256, 0, stream>>>(u, modes, states, Dscal, y);
}

extern "C" void kernel_launch(void* const* d_in, const int* in_sizes, int n_in,
                              void* d_out, int out_size, void* d_ws, size_t ws_size,
                              hipStream_t stream) {
    const float* u      = (const float*)d_in[0];
    const float* log_dt = (const float*)d_in[1];
    const float* A_real = (const float*)d_in[2];
    const float* A_imag = (const float*)d_in[3];
    const float* C_real = (const float*)d_in[4];
    const float* C_imag = (const float*)d_in[5];
    const float* Dscal  = (const float*)d_in[6];
    float* y = (float*)d_out;
    char* ws = (char*)d_ws;

    const size_t base = 786432;
    auto need = [&](int C) { return base + (size_t)B_ * C * N_ * H_ * 8; };
    if (ws_size >= need(32)) {
        launch_all<32>(u, log_dt, A_real, A_imag, C_real, C_imag, Dscal, y, ws, stream);
    } else if (ws_size >= need(16)) {
        launch_all<16>(u, log_dt, A_real, A_imag, C_real, C_imag, Dscal, y, ws, stream);
    } else {
        launch_all<8>(u, log_dt, A_real, A_imag, C_real, C_imag, Dscal, y, ws, stream);
    }
}

// Round 7
// 489.468 us; speedup vs baseline: 1.0762x; 1.0762x over previous
//
#include <hip/hip_runtime.h>

// S4D: B=8, L=4096, H=1024, N=32 complex modes. f32 in / f32 out.
// R11: kill AGPR-parking by keeping peak live-set <= ~48 regs.
// Evidence: R10 (LDS constants) kept VGPR=40 but occupancy 54% ~= 4.3 waves/SIMD
// => true unified-file alloc ~112 regs/wave: ~70 AGPRs + v_accvgpr_read/write
// moves = the measured ~2x VALU issue (460 slots/body vs ~235 in source).
// Fixes: (1) mode constants read ONE float4/float2 per mode inside the FMA loop
// (transient, pipelined ds_reads at immediate offsets) -- no 32-reg mm block;
// (2) plain __launch_bounds__(256), no waves_per_eu -> allocator free to choose
// an occupancy it can satisfy with ZERO parking; (3) blockIdx swizzle putting
// (ht, ht^1) partner blocks 8 apart in dispatch id -> same XCD -> L2 merges the
// 64B half-line u reads (R10 FETCH regression 98->165 MB).

#define B_ 8
#define L_ 4096
#define H_ 1024
#define N_ 32
#define NQ_ 8   // modes per lane (N_/4, 4 lane-groups per h)

// ---------------- kernel A: per-(h,n) mode constants ----------------
// modes[n*H+h] = (w_r, w_i, g_r, g_i); w = exp(dt*A); g = (2 Re C', -2 Im C');
// C' = (C_r + i C_i)*(w-1)/A.  wLc[n*H+h] = w^(Lc).
__global__ void modes_kernel(const float* __restrict__ log_dt,
                             const float* __restrict__ A_real,
                             const float* __restrict__ A_imag,
                             const float* __restrict__ C_real,
                             const float* __restrict__ C_imag,
                             float4* __restrict__ modes,
                             float2* __restrict__ wLc,
                             int log2Lc) {
    int t = blockIdx.x * blockDim.x + threadIdx.x;
    if (t >= H_ * N_) return;
    int h = t / N_, n = t % N_;
    float dt = expf(log_dt[h]);
    float ar = -expf(A_real[t]);
    float ai = A_imag[t];
    float cr = C_real[t];
    float ci = C_imag[t];
    float dr = ar * dt, di = ai * dt;
    float e = expf(dr);
    float sn, cs;
    sincosf(di, &sn, &cs);
    float wr = e * cs, wi = e * sn;
    float inv = 1.0f / (ar * ar + ai * ai);
    float nr = wr - 1.0f, ni = wi;
    float qr = (nr * ar + ni * ai) * inv;
    float qi = (ni * ar - nr * ai) * inv;
    float gr = 2.0f * (cr * qr - ci * qi);
    float gi = -2.0f * (cr * qi + ci * qr);
    modes[n * H_ + h] = make_float4(wr, wi, gr, gi);
    float pr = wr, pi2 = wi;
    for (int i = 0; i < log2Lc; ++i) {
        float t2r = pr * pr - pi2 * pi2;
        float t2i = 2.0f * pr * pi2;
        pr = t2r; pi2 = t2i;
    }
    wLc[n * H_ + h] = make_float2(pr, pi2);
}

// Block swizzle: role = bcq*64 + ht; dispatch id packs ht bit0 at bit3 so the
// (ht, ht^1) pair differs by 8 => same XCD under round-robin id%8.
// id bits: [2:0]=bcq low3, [3]=ht bit0, [8:4]=ht>>1, [>=9]=bcq>>3.
#define UNSWIZZLE_BLOCK()                                                       \
    unsigned bid = blockIdx.x;                                                  \
    int bcq = (int)((bid & 7u) | ((bid >> 9) << 3));                            \
    int ht = (int)(((bid >> 3) & 1u) | (((bid >> 4) & 31u) << 1));

// Wave wv = tid>>6: bc = bcq*4 + wv. Lane: q = lane>>4 (mode quarter, 8 modes),
// k = lane&15 (h within tile). idx = bc*Lc*H + h (since b*L + c*Lc = bc*Lc).

// 4 steps of the state recurrence for 8 modes; constants read per-mode from LDS
// (transient float2, immediate-offset ds_reads -> no 16-reg block live).
#define SLOC_BODY(U0, U1, U2, U3, DO_PF) do {                                   \
    asm volatile("" : "+v"(soff));  /* launder: defeat cross-body CSE/LICM */   \
    const float2* sp_ = smw + soff;                                             \
    _Pragma("unroll")                                                           \
    for (int n = 0; n < NQ_; ++n) {                                             \
        const float2 m = sp_[n * 16];                                           \
        const float wrn = m.x, win = m.y;                                       \
        float t1r = fmaf(wrn, sr[n], fmaf(-win, si[n], (U0)));                  \
        float t1i = fmaf(wrn, si[n], win * sr[n]);                              \
        float t2r = fmaf(wrn, t1r, fmaf(-win, t1i, (U1)));                      \
        float t2i = fmaf(wrn, t1i, win * t1r);                                  \
        float t3r = fmaf(wrn, t2r, fmaf(-win, t2i, (U2)));                      \
        float t3i = fmaf(wrn, t2i, win * t2r);                                  \
        float t4r = fmaf(wrn, t3r, fmaf(-win, t3i, (U3)));                      \
        float t4i = fmaf(wrn, t3i, win * t3r);                                  \
        sr[n] = t4r; si[n] = t4i;                                               \
    }                                                                           \
    if (DO_PF) {                                                                \
        (U0) = u[pf]; (U1) = u[pf + H_]; (U2) = u[pf + 2u * H_];                \
        (U3) = u[pf + 3u * H_];                                                 \
        pf += 4u * H_;                                                          \
    }                                                                           \
} while (0)

// ---------------- kernel B: local scan per chunk (zero entry state) ----------------
template <int C_>
__global__ __launch_bounds__(256) void scan_local(const float* __restrict__ u,
                                                  const float4* __restrict__ modes,
                                                  float2* __restrict__ states) {
    constexpr int Lc = L_ / C_;
    __shared__ float2 smw[N_ * 16];  // [n][k], 4 KiB
    int tid = threadIdx.x;
    UNSWIZZLE_BLOCK();
    int bc = bcq * 4 + (tid >> 6);
    int lane = tid & 63;
    int q = lane >> 4;
    int k = lane & 15;
    int h = ht * 16 + k;
    int nb = q * NQ_;
    for (int i = tid; i < N_ * 16; i += 256) {
        float4 m = modes[(i >> 4) * H_ + ht * 16 + (i & 15)];
        smw[i] = make_float2(m.x, m.y);
    }
    __syncthreads();
    float sr[NQ_], si[NQ_];
#pragma unroll
    for (int n = 0; n < NQ_; ++n) { sr[n] = 0.0f; si[n] = 0.0f; }
    unsigned soff = (unsigned)(nb * 16 + k);
    unsigned idx = (unsigned)bc * (unsigned)(Lc * H_) + (unsigned)h;
    float a0 = u[idx];
    float a1 = u[idx + H_];
    float a2 = u[idx + 2u * H_];
    float a3 = u[idx + 3u * H_];
    float b0 = u[idx + 4u * H_];
    float b1 = u[idx + 5u * H_];
    float b2 = u[idx + 6u * H_];
    float b3 = u[idx + 7u * H_];
    unsigned pf = idx + 8u * H_;
    for (int j = 0; j + 8 < Lc; j += 8) {
        SLOC_BODY(a0, a1, a2, a3, 1);
        SLOC_BODY(b0, b1, b2, b3, 1);
    }
    SLOC_BODY(a0, a1, a2, a3, 0);
    SLOC_BODY(b0, b1, b2, b3, 0);
    float2* sp = states + ((size_t)bc * N_ + nb) * H_ + h;
#pragma unroll
    for (int n = 0; n < NQ_; ++n) sp[(size_t)n * H_] = make_float2(sr[n], si[n]);
}

// ---------------- kernel C: cross-chunk scan (in place: local-end -> entry) --------
template <int C_>
__global__ __launch_bounds__(256) void chunk_scan(const float2* __restrict__ wLc,
                                                  float2* __restrict__ states) {
    int t = blockIdx.x * blockDim.x + threadIdx.x;
    int h = t % H_;
    int bn = t / H_;
    int n = bn % N_;
    int b = bn / N_;
    float2 wl = wLc[n * H_ + h];
    float er = 0.0f, ei = 0.0f;
    float2* p0 = states + ((size_t)(b * C_) * N_ + n) * H_ + h;
    const size_t stride = (size_t)N_ * H_;
    float2 nxt = *p0;
#pragma unroll
    for (int c = 0; c < C_; ++c) {
        float2 le = nxt;
        float2* p = p0 + (size_t)c * stride;
        if (c + 1 < C_) nxt = p[stride];  // prefetch next before FMA/store
        *p = make_float2(er, ei);
        float nr2 = fmaf(wl.x, er, fmaf(-wl.y, ei, le.x));
        float ni2 = fmaf(wl.x, ei, fmaf(wl.y, er, le.y));
        er = nr2; ei = ni2;
    }
}

// 4 steps + g-accumulate + 4x4 transpose-reduce + gelu/store (one row per quarter);
// constants read per-mode from LDS (transient float4).
#define SOUT_BODY(U0, U1, U2, U3, DO_PF) do {                                   \
    asm volatile("" : "+v"(soff));  /* launder: defeat cross-body CSE/LICM */   \
    const float4* sp_ = smodes + soff;                                          \
    float accA = 0.0f, accB = 0.0f, accC = 0.0f, accD = 0.0f;                   \
    _Pragma("unroll")                                                           \
    for (int n = 0; n < NQ_; ++n) {                                             \
        const float4 m = sp_[n * 16];                                           \
        const float wrn = m.x, win = m.y, grn = m.z, gin = m.w;                 \
        float t1r = fmaf(wrn, sr[n], fmaf(-win, si[n], (U0)));                  \
        float t1i = fmaf(wrn, si[n], win * sr[n]);                              \
        accA = fmaf(grn, t1r, fmaf(gin, t1i, accA));                            \
        float t2r = fmaf(wrn, t1r, fmaf(-win, t1i, (U1)));                      \
        float t2i = fmaf(wrn, t1i, win * t1r);                                  \
        accB = fmaf(grn, t2r, fmaf(gin, t2i, accB));                            \
        float t3r = fmaf(wrn, t2r, fmaf(-win, t2i, (U2)));                      \
        float t3i = fmaf(wrn, t2i, win * t2r);                                  \
        accC = fmaf(grn, t3r, fmaf(gin, t3i, accC));                            \
        float t4r = fmaf(wrn, t3r, fmaf(-win, t3i, (U3)));                      \
        float t4i = fmaf(wrn, t3i, win * t3r);                                  \
        accD = fmaf(grn, t4r, fmaf(gin, t4i, accD));                            \
        sr[n] = t4r; si[n] = t4i;                                               \
    }                                                                           \
    /* stage 1 (xor 32): pair-sum A with A, B with B across half-groups */      \
    float r0 = hiq ? accC : accA;                                               \
    float r1 = hiq ? accA : accC;                                               \
    float p0 = r0 + __shfl_xor(r1, 32, 64);                                     \
    float r2 = hiq ? accD : accB;                                               \
    float r3 = hiq ? accB : accD;                                               \
    float p1 = r2 + __shfl_xor(r3, 32, 64);                                     \
    /* stage 2 (xor 16): each quarter ends with its own step's total */         \
    float snd = oddq ? p0 : p1;                                                 \
    float bse = oddq ? p1 : p0;                                                 \
    float accS = bse + __shfl_xor(snd, 16, 64);                                 \
    float uv01 = oddq ? (U1) : (U0);                                            \
    float uv23 = oddq ? (U3) : (U2);                                            \
    float uvS = hiq ? uv23 : uv01;                                              \
    float v = fmaf(Dv, uvS, accS);                                              \
    float g = 0.5f * v * (1.0f + erff(v * 0.70710678118654752f));               \
    y[sy] = g;                                                                  \
    sy += 4u * H_;                                                              \
    if (DO_PF) {                                                                \
        (U0) = u[pf]; (U1) = u[pf + H_]; (U2) = u[pf + 2u * H_];                \
        (U3) = u[pf + 3u * H_];                                                 \
        pf += 4u * H_;                                                          \
    }                                                                           \
} while (0)

// ---------------- kernel D: re-scan with entry state, emit gelu(y) ----------------
template <int C_>
__global__ __launch_bounds__(256)
void scan_out(const float* __restrict__ u,
              const float4* __restrict__ modes,
              const float2* __restrict__ states,
              const float* __restrict__ Dscal,
              float* __restrict__ y) {
    constexpr int Lc = L_ / C_;
    __shared__ float4 smodes[N_ * 16];  // [n][k], 8 KiB
    int tid = threadIdx.x;
    UNSWIZZLE_BLOCK();
    int bc = bcq * 4 + (tid >> 6);
    int lane = tid & 63;
    int q = lane >> 4;
    int k = lane & 15;
    int h = ht * 16 + k;
    int nb = q * NQ_;
    bool hiq = (lane & 32) != 0;   // quarter in {2,3}
    bool oddq = (lane & 16) != 0;  // quarter odd
    float Dv = Dscal[0];
    for (int i = tid; i < N_ * 16; i += 256) {
        smodes[i] = modes[(i >> 4) * H_ + ht * 16 + (i & 15)];
    }
    __syncthreads();
    float sr[NQ_], si[NQ_];
#pragma unroll
    for (int n = 0; n < NQ_; ++n) {
        float2 e = states[((size_t)bc * N_ + nb + n) * H_ + h];
        sr[n] = e.x; si[n] = e.y;
    }
    unsigned soff = (unsigned)(nb * 16 + k);
    unsigned idx = (unsigned)bc * (unsigned)(Lc * H_) + (unsigned)h;
    unsigned sy = idx + (unsigned)(q * H_);
    float a0 = u[idx];
    float a1 = u[idx + H_];
    float a2 = u[idx + 2u * H_];
    float a3 = u[idx + 3u * H_];
    float b0 = u[idx + 4u * H_];
    float b1 = u[idx + 5u * H_];
    float b2 = u[idx + 6u * H_];
    float b3 = u[idx + 7u * H_];
    unsigned pf = idx + 8u * H_;
    for (int j = 0; j + 8 < Lc; j += 8) {
        SOUT_BODY(a0, a1, a2, a3, 1);
        SOUT_BODY(b0, b1, b2, b3, 1);
    }
    SOUT_BODY(a0, a1, a2, a3, 0);
    SOUT_BODY(b0, b1, b2, b3, 0);
}

// ---------------- launcher ----------------
template <int C_>
static void launch_all(const float* u, const float* log_dt, const float* A_real,
                       const float* A_imag, const float* C_real, const float* C_imag,
                       const float* Dscal, float* y, char* ws, hipStream_t stream) {
    float4* modes = (float4*)ws;                        // H*N*16 = 512 KiB
    float2* wLc   = (float2*)(ws + 524288);             // H*N*8  = 256 KiB
    float2* states = (float2*)(ws + 786432);            // B*C*N*H*8
    int log2Lc = 0;
    for (int v = L_ / C_; v > 1; v >>= 1) ++log2Lc;

    // blocks: (B*C/4) bc-groups x 64 h-tiles; 4 waves/block share one h-tile
    constexpr int nblocks = (B_ * C_ / 4) * 64;

    modes_kernel<<<(H_ * N_) / 256, 256, 0, stream>>>(log_dt, A_real, A_imag,
                                                      C_real, C_imag, modes, wLc, log2Lc);
    scan_local<C_><<<nblocks, 256, 0, stream>>>(u, modes, states);
    chunk_scan<C_><<<(B_ * N_ * H_) / 256, 256, 0, stream>>>(wLc, states);
    scan_out<C_><<<nblocks, 256, 0, stream>>>(u, modes, states, Dscal, y);
}

extern "C" void kernel_launch(void* const* d_in, const int* in_sizes, int n_in,
                              void* d_out, int out_size, void* d_ws, size_t ws_size,
                              hipStream_t stream) {
    const float* u      = (const float*)d_in[0];
    const float* log_dt = (const float*)d_in[1];
    const float* A_real = (const float*)d_in[2];
    const float* A_imag = (const float*)d_in[3];
    const float* C_real = (const float*)d_in[4];
    const float* C_imag = (const float*)d_in[5];
    const float* Dscal  = (const float*)d_in[6];
    float* y = (float*)d_out;
    char* ws = (char*)d_ws;

    const size_t base = 786432;
    auto need = [&](int C) { return base + (size_t)B_ * C * N_ * H_ * 8; };
    if (ws_size >= need(32)) {
        launch_all<32>(u, log_dt, A_real, A_imag, C_real, C_imag, Dscal, y, ws, stream);
    } else if (ws_size >= need(16)) {
        launch_all<16>(u, log_dt, A_real, A_imag, C_real, C_imag, Dscal, y, ws, stream);
    } else {
        launch_all<8>(u, log_dt, A_real, A_imag, C_real, C_imag, Dscal, y, ws, stream);
    }
}